// Round 2
// baseline (980.209 us; speedup 1.0000x reference)
//
#include <hip/hip_runtime.h>
#include <cstdint>
#include <cstddef>

#define NNODES 100000
#define NEDGES 3200000
#define NF 128

// ================= CSR build =================

__global__ void k_hist(const int* __restrict__ recv, int* __restrict__ counts) {
  int stride = gridDim.x * blockDim.x;
  for (int i = blockIdx.x * blockDim.x + threadIdx.x; i < NEDGES; i += stride)
    atomicAdd(&counts[recv[i]], 1);
}

#define SCHUNK 2048
#define SNB ((NNODES + SCHUNK - 1) / SCHUNK)  // 49

__global__ void k_scan1(const int* __restrict__ counts, int* __restrict__ offs,
                        int* __restrict__ partials) {
  __shared__ int sd[256];
  int t = threadIdx.x;
  int base = blockIdx.x * SCHUNK + t * 8;
  int v[8];
  int s = 0;
#pragma unroll
  for (int j = 0; j < 8; ++j) {
    int idx = base + j;
    int c = (idx < NNODES) ? counts[idx] : 0;
    v[j] = s;
    s += c;
  }
  sd[t] = s;
  __syncthreads();
  for (int off = 1; off < 256; off <<= 1) {
    int x = (t >= off) ? sd[t - off] : 0;
    __syncthreads();
    sd[t] += x;
    __syncthreads();
  }
  int excl = sd[t] - s;  // exclusive prefix of this thread's chunk within block
#pragma unroll
  for (int j = 0; j < 8; ++j) {
    int idx = base + j;
    if (idx < NNODES) offs[idx] = excl + v[j];
  }
  if (t == 255) partials[blockIdx.x] = sd[255];
}

__global__ void k_scan2(int* __restrict__ partials, int* __restrict__ offs) {
  if (threadIdx.x == 0 && blockIdx.x == 0) {
    int run = 0;
    for (int i = 0; i < SNB; ++i) {
      int tv = partials[i];
      partials[i] = run;
      run += tv;
    }
    offs[NNODES] = run;  // == NEDGES
  }
}

__global__ void k_scan3(int* __restrict__ offs, const int* __restrict__ partials,
                        int* __restrict__ cursor) {
  int i = blockIdx.x * blockDim.x + threadIdx.x;
  if (i < NNODES) {
    int v = offs[i] + partials[i / SCHUNK];
    offs[i] = v;
    cursor[i] = v;
  }
}

__global__ void k_scatter(const int* __restrict__ send, const int* __restrict__ recv,
                          const float* __restrict__ ev, int* __restrict__ cursor,
                          int2* __restrict__ csr) {
  int stride = gridDim.x * blockDim.x;
  for (int i = blockIdx.x * blockDim.x + threadIdx.x; i < NEDGES; i += stride) {
    int r = recv[i];
    int pos = atomicAdd(&cursor[r], 1);
    csr[pos] = make_int2(send[i], __float_as_int(ev[i]));
  }
}

// ================= dense GEMM: Y[N,128] = X[N,128] @ W[128,128] =================
// block = 256 threads, 32-row tile, thread computes 4x4. W + transposed x tile in LDS.
// LDS = 64KB + 16KB = 80KB -> 2 blocks/CU.
__global__ __launch_bounds__(256, 2) void k_gemm(const float* __restrict__ X,
                                                 const float* __restrict__ W,
                                                 float* __restrict__ Y) {
  __shared__ float sW[128 * 128];
  __shared__ float sXT[128][32];  // [k][row]
  const int t = threadIdx.x;
  for (int i = t * 4; i < 128 * 128; i += 1024)
    *reinterpret_cast<float4*>(&sW[i]) = *reinterpret_cast<const float4*>(&W[i]);
  const int r0 = blockIdx.x * 32;
  {
    const int rr = t >> 3;          // 0..31
    const int kk = (t & 7) * 16;    // 0,16,...,112
    const float* xp = X + (size_t)(r0 + rr) * NF + kk;
    float4 a = *reinterpret_cast<const float4*>(xp + 0);
    float4 b = *reinterpret_cast<const float4*>(xp + 4);
    float4 c = *reinterpret_cast<const float4*>(xp + 8);
    float4 d = *reinterpret_cast<const float4*>(xp + 12);
    sXT[kk + 0][rr] = a.x;  sXT[kk + 1][rr] = a.y;  sXT[kk + 2][rr] = a.z;  sXT[kk + 3][rr] = a.w;
    sXT[kk + 4][rr] = b.x;  sXT[kk + 5][rr] = b.y;  sXT[kk + 6][rr] = b.z;  sXT[kk + 7][rr] = b.w;
    sXT[kk + 8][rr] = c.x;  sXT[kk + 9][rr] = c.y;  sXT[kk + 10][rr] = c.z; sXT[kk + 11][rr] = c.w;
    sXT[kk + 12][rr] = d.x; sXT[kk + 13][rr] = d.y; sXT[kk + 14][rr] = d.z; sXT[kk + 15][rr] = d.w;
  }
  __syncthreads();
  const int tc = t & 31;   // col group
  const int tr = t >> 5;   // row group
  const int c0 = tc * 4;
  const int rr0 = tr * 4;
  float acc[4][4] = {};
#pragma unroll 4
  for (int k = 0; k < 128; ++k) {
    float4 xv = *reinterpret_cast<const float4*>(&sXT[k][rr0]);
    float4 wv = *reinterpret_cast<const float4*>(&sW[k * 128 + c0]);
    acc[0][0] += xv.x * wv.x; acc[0][1] += xv.x * wv.y; acc[0][2] += xv.x * wv.z; acc[0][3] += xv.x * wv.w;
    acc[1][0] += xv.y * wv.x; acc[1][1] += xv.y * wv.y; acc[1][2] += xv.y * wv.z; acc[1][3] += xv.y * wv.w;
    acc[2][0] += xv.z * wv.x; acc[2][1] += xv.z * wv.y; acc[2][2] += xv.z * wv.z; acc[2][3] += xv.z * wv.w;
    acc[3][0] += xv.w * wv.x; acc[3][1] += xv.w * wv.y; acc[3][2] += xv.w * wv.z; acc[3][3] += xv.w * wv.w;
  }
#pragma unroll
  for (int i = 0; i < 4; ++i) {
    float4 o = make_float4(acc[i][0], acc[i][1], acc[i][2], acc[i][3]);
    *reinterpret_cast<float4*>(&Y[(size_t)(r0 + rr0 + i) * NF + c0]) = o;
  }
}

// ================= SpMM + bias + relu: out[r,:] = relu(sum_e v*supp[s,:] + b) =======
// one wave (64 lanes) per node, 2 features per lane (float2)
__global__ __launch_bounds__(256) void k_spmm_relu(const float* __restrict__ supp,
                                                   const int2* __restrict__ csr,
                                                   const int* __restrict__ offs,
                                                   const int* __restrict__ counts,
                                                   const float* __restrict__ bias,
                                                   float* __restrict__ out) {
  const int wid = (blockIdx.x * 256 + threadIdx.x) >> 6;
  const int lane = threadIdx.x & 63;
  if (wid >= NNODES) return;
  const int start = offs[wid];
  const int deg = counts[wid];
  const float2 bv = *reinterpret_cast<const float2*>(&bias[lane * 2]);
  const int2* e = csr + start;
  float2 acc = make_float2(0.f, 0.f);
  int i = 0;
  for (; i + 4 <= deg; i += 4) {
    int2 e0 = e[i + 0];
    int2 e1 = e[i + 1];
    int2 e2 = e[i + 2];
    int2 e3 = e[i + 3];
    float2 h0 = *reinterpret_cast<const float2*>(supp + (size_t)e0.x * NF + lane * 2);
    float2 h1 = *reinterpret_cast<const float2*>(supp + (size_t)e1.x * NF + lane * 2);
    float2 h2 = *reinterpret_cast<const float2*>(supp + (size_t)e2.x * NF + lane * 2);
    float2 h3 = *reinterpret_cast<const float2*>(supp + (size_t)e3.x * NF + lane * 2);
    float v0 = __int_as_float(e0.y), v1 = __int_as_float(e1.y);
    float v2 = __int_as_float(e2.y), v3 = __int_as_float(e3.y);
    acc.x += v0 * h0.x; acc.y += v0 * h0.y;
    acc.x += v1 * h1.x; acc.y += v1 * h1.y;
    acc.x += v2 * h2.x; acc.y += v2 * h2.y;
    acc.x += v3 * h3.x; acc.y += v3 * h3.y;
  }
  for (; i < deg; ++i) {
    int2 e0 = e[i];
    float2 h0 = *reinterpret_cast<const float2*>(supp + (size_t)e0.x * NF + lane * 2);
    float v0 = __int_as_float(e0.y);
    acc.x += v0 * h0.x; acc.y += v0 * h0.y;
  }
  float2 o;
  o.x = fmaxf(acc.x + bv.x, 0.f);
  o.y = fmaxf(acc.y + bv.y, 0.f);
  *reinterpret_cast<float2*>(&out[(size_t)wid * NF + lane * 2]) = o;
}

// ================= launch =================
extern "C" void kernel_launch(void* const* d_in, const int* in_sizes, int n_in,
                              void* d_out, int out_size, void* d_ws, size_t ws_size,
                              hipStream_t stream) {
  const float* x = (const float*)d_in[0];
  const int* senders = (const int*)d_in[1];
  const int* recv = (const int*)d_in[2];
  const float* ev = (const float*)d_in[3];
  const float* W1 = (const float*)d_in[4];
  const float* b1 = (const float*)d_in[5];
  const float* W2 = (const float*)d_in[6];
  const float* b2 = (const float*)d_in[7];
  float* out = (float*)d_out;

  char* ws = (char*)d_ws;
  float* supp = (float*)ws;                            // N*128 f32 = 51,200,000 B
  int2* csr = (int2*)(ws + 51200000);                  // E int2  = 25,600,000 B
  int* offs = (int*)(ws + 76800000);                   // (N+1) ints
  int* counts = (int*)(ws + 77200016);                 // N ints
  int* cursor = (int*)(ws + 77600016);                 // N ints
  int* partials = (int*)(ws + 78000016);               // SNB ints

  hipMemsetAsync(counts, 0, NNODES * sizeof(int), stream);
  k_hist<<<2048, 256, 0, stream>>>(recv, counts);
  k_scan1<<<SNB, 256, 0, stream>>>(counts, offs, partials);
  k_scan2<<<1, 64, 0, stream>>>(partials, offs);
  k_scan3<<<(NNODES + 255) / 256, 256, 0, stream>>>(offs, partials, cursor);
  k_scatter<<<2048, 256, 0, stream>>>(senders, recv, ev, cursor, csr);

  // layer 1: supp = x @ W1 ; h1 = relu(A supp + b1) -> stored in d_out
  k_gemm<<<NNODES / 32, 256, 0, stream>>>(x, W1, supp);
  k_spmm_relu<<<(NNODES * 64 + 255) / 256, 256, 0, stream>>>(supp, csr, offs, counts, b1, out);
  // layer 2: supp = h1 @ W2 ; out = relu(A supp + b2)
  k_gemm<<<NNODES / 32, 256, 0, stream>>>(out, W2, supp);
  k_spmm_relu<<<(NNODES * 64 + 255) / 256, 256, 0, stream>>>(supp, csr, offs, counts, b2, out);
}

// Round 3
// 727.617 us; speedup vs baseline: 1.3471x; 1.3471x over previous
//
#include <hip/hip_runtime.h>
#include <cstdint>
#include <cstddef>

#define NNODES 100000
#define NEDGES 3200000
#define NF 128
#define BSHIFT 5
#define BWID 32
#define NBUCK 3125   // 100000/32 exactly

typedef __attribute__((ext_vector_type(8))) short short8v;
typedef __attribute__((ext_vector_type(4))) float float4v;

static __device__ __forceinline__ uint16_t f2bf(float f) {
  uint32_t u = __float_as_uint(f);
  return (uint16_t)((u + 0x7fffu + ((u >> 16) & 1u)) >> 16);  // RNE
}
static __device__ __forceinline__ float bflo(uint32_t u) { return __uint_as_float(u << 16); }
static __device__ __forceinline__ float bfhi(uint32_t u) { return __uint_as_float(u & 0xffff0000u); }

// ============ bucket histogram (LDS-privatized) ============
#define HBLK 256
__global__ __launch_bounds__(256) void k_bhist(const int* __restrict__ recv,
                                               int* __restrict__ bcount) {
  __shared__ int h[NBUCK];
  for (int i = threadIdx.x; i < NBUCK; i += 256) h[i] = 0;
  __syncthreads();
  const int stride = HBLK * 256;
  for (int i = blockIdx.x * 256 + threadIdx.x; i < NEDGES; i += stride)
    atomicAdd(&h[recv[i] >> BSHIFT], 1);
  __syncthreads();
  for (int i = threadIdx.x; i < NBUCK; i += 256) {
    int v = h[i];
    if (v) atomicAdd(&bcount[i], v);
  }
}

// ============ bucket exclusive scan (single block) ============
__global__ __launch_bounds__(1024) void k_bscan(const int* __restrict__ bcount,
                                                int* __restrict__ boffs,
                                                int* __restrict__ bcursor) {
  __shared__ int sd[1024];
  int t = threadIdx.x;
  int v[4];
  int s = 0;
#pragma unroll
  for (int j = 0; j < 4; ++j) {
    int idx = t * 4 + j;
    int c = (idx < NBUCK) ? bcount[idx] : 0;
    v[j] = s;
    s += c;
  }
  sd[t] = s;
  __syncthreads();
  for (int off = 1; off < 1024; off <<= 1) {
    int x = (t >= off) ? sd[t - off] : 0;
    __syncthreads();
    sd[t] += x;
    __syncthreads();
  }
  int excl = sd[t] - s;
#pragma unroll
  for (int j = 0; j < 4; ++j) {
    int idx = t * 4 + j;
    if (idx < NBUCK) {
      int o = excl + v[j];
      boffs[idx] = o;
      bcursor[idx] = o;
    }
  }
  if (t == 1023) boffs[NBUCK] = sd[1023];
}

// ============ pass 1: append edges into bucket regions ============
__global__ __launch_bounds__(256) void k_pass1(const int* __restrict__ send,
                                               const int* __restrict__ recv,
                                               const float* __restrict__ ev,
                                               int* __restrict__ bcursor,
                                               uint2* __restrict__ buf) {
  const int stride = gridDim.x * 256;
  for (int i = blockIdx.x * 256 + threadIdx.x; i < NEDGES; i += stride) {
    int r = recv[i];
    int pos = atomicAdd(&bcursor[r >> BSHIFT], 1);
    buf[pos] = make_uint2((uint32_t)send[i] | ((uint32_t)(r & (BWID - 1)) << 17),
                          __float_as_uint(ev[i]));
  }
}

// ============ pass 2: per-bucket local sort -> final CSR + offs/counts ============
__global__ __launch_bounds__(256) void k_pass2(const uint2* __restrict__ buf,
                                               const int* __restrict__ boffs,
                                               int* __restrict__ offs,
                                               int* __restrict__ counts,
                                               int2* __restrict__ csr) {
  __shared__ int hcnt[BWID], hoff[BWID], sd[BWID];
  const int b = blockIdx.x, t = threadIdx.x;
  const int bstart = boffs[b], bend = boffs[b + 1];
  const int nb = bend - bstart;
  if (t < BWID) hcnt[t] = 0;
  __syncthreads();
  for (int i = t; i < nb; i += 256) atomicAdd(&hcnt[buf[bstart + i].x >> 17], 1);
  __syncthreads();
  int v = (t < BWID) ? hcnt[t] : 0;
  if (t < BWID) sd[t] = v;
  __syncthreads();
  for (int off = 1; off < BWID; off <<= 1) {
    int x = (t >= off && t < BWID) ? sd[t - off] : 0;
    __syncthreads();
    if (t < BWID) sd[t] += x;
    __syncthreads();
  }
  if (t < BWID) {
    int excl = sd[t] - v;
    hoff[t] = excl;
    int node = b * BWID + t;  // NBUCK*BWID == NNODES exactly
    offs[node] = bstart + excl;
    counts[node] = v;
    hcnt[t] = 0;  // reuse as cursor
  }
  __syncthreads();
  for (int i = t; i < nb; i += 256) {
    uint2 e = buf[bstart + i];
    uint32_t rl = e.x >> 17;
    int pos = bstart + hoff[rl] + atomicAdd(&hcnt[rl], 1);
    csr[pos] = make_int2((int)(e.x & 0x1FFFFu), (int)e.y);
  }
}

// ============ W -> bf16, transposed [n][k] ============
__global__ __launch_bounds__(256) void k_wprep(const float* __restrict__ W1,
                                               const float* __restrict__ W2,
                                               uint16_t* __restrict__ wT) {
  const float* W = blockIdx.x ? W2 : W1;
  uint16_t* o = wT + blockIdx.x * 16384;
  for (int i = threadIdx.x; i < 16384; i += 256) {
    int k = i >> 7, n = i & 127;
    o[n * 128 + k] = f2bf(W[i]);
  }
}

// ============ MFMA bf16 GEMM: Y[N,128](bf16) = X[N,128] @ W  ============
// block 256 = 4 waves, 64-row tile, K=128 fully staged. XOR-swizzled LDS (T2).
template <bool XF32>
__global__ __launch_bounds__(256) void k_gemm(const void* __restrict__ Xv,
                                              const uint16_t* __restrict__ wT,
                                              uint16_t* __restrict__ Y) {
  __shared__ uint16_t sX[64 * 128];
  __shared__ uint16_t sWT[128 * 128];  // [n][k], swizzled 16B chunks
  const int t = threadIdx.x;
  const int r0 = blockIdx.x * 64;
  {  // stage W (pre-transposed bf16 in global): linear copy w/ chunk swizzle
    const uint4* src = (const uint4*)wT;
    uint4* dst = (uint4*)sWT;
#pragma unroll
    for (int j = 0; j < 8; ++j) {
      int i = j * 256 + t;
      int row = i >> 4;
      dst[(i & ~15) | ((i & 15) ^ (row & 7))] = src[i];
    }
  }
  if (XF32) {  // stage X from f32, convert
    const float* X = (const float*)Xv;
    int r = t >> 2, c0 = (t & 3) * 32;
    int grow = r0 + r;
    if (grow >= NNODES) grow = NNODES - 1;
    const float* xp = X + (size_t)grow * 128 + c0;
    uint4* xdst = (uint4*)sX;
#pragma unroll
    for (int j = 0; j < 4; ++j) {
      float4 f0 = *(const float4*)(xp + j * 8);
      float4 f1 = *(const float4*)(xp + j * 8 + 4);
      uint4 vv;
      vv.x = (uint32_t)f2bf(f0.x) | ((uint32_t)f2bf(f0.y) << 16);
      vv.y = (uint32_t)f2bf(f0.z) | ((uint32_t)f2bf(f0.w) << 16);
      vv.z = (uint32_t)f2bf(f1.x) | ((uint32_t)f2bf(f1.y) << 16);
      vv.w = (uint32_t)f2bf(f1.z) | ((uint32_t)f2bf(f1.w) << 16);
      int kc = (c0 >> 3) + j;
      xdst[r * 16 + (kc ^ (r & 7))] = vv;
    }
  } else {  // stage X from bf16, straight copy
    const uint4* src = (const uint4*)((const char*)Xv + (size_t)r0 * 256);
    uint4* xdst = (uint4*)sX;
    size_t maxByte = (size_t)NNODES * 256 - (size_t)r0 * 256;
#pragma unroll
    for (int j = 0; j < 4; ++j) {
      int i = j * 256 + t;
      int row = i >> 4;
      uint4 vv = ((size_t)i * 16 < maxByte) ? src[i] : make_uint4(0, 0, 0, 0);
      xdst[(i & ~15) | ((i & 15) ^ (row & 7))] = vv;
    }
  }
  __syncthreads();
  const int l = t & 63, w = t >> 6;
  const int m16 = l & 15, kb = l >> 4;
  const int arow = w * 16 + m16;
  short8v a[4];
#pragma unroll
  for (int ks = 0; ks < 4; ++ks) {
    int elem = (ks * 32 + kb * 8) ^ ((arow & 7) << 3);
    a[ks] = *reinterpret_cast<const short8v*>(&sX[arow * 128 + elem]);
  }
  float4v acc[8] = {};
#pragma unroll
  for (int nt = 0; nt < 8; ++nt) {
    int brow = nt * 16 + m16;
    int bswz = (brow & 7) << 3;
    int bbase = brow * 128;
#pragma unroll
    for (int ks = 0; ks < 4; ++ks) {
      short8v bb = *reinterpret_cast<const short8v*>(&sWT[bbase + ((ks * 32 + kb * 8) ^ bswz)]);
      acc[nt] = __builtin_amdgcn_mfma_f32_16x16x32_bf16(a[ks], bb, acc[nt], 0, 0, 0);
    }
  }
  // C/D layout (m89-verified): col = lane&15, row = (lane>>4)*4 + reg
  const int orow0 = r0 + w * 16 + kb * 4;
#pragma unroll
  for (int nt = 0; nt < 8; ++nt) {
    int col = nt * 16 + m16;
#pragma unroll
    for (int q = 0; q < 4; ++q) {
      int grow = orow0 + q;
      if (grow < NNODES) Y[(size_t)grow * 128 + col] = f2bf(acc[nt][q]);
    }
  }
}

// ============ SpMM + bias + relu (bf16 gather, 4B/lane) ============
template <bool OUTBF>
__global__ __launch_bounds__(256) void k_spmm(const uint32_t* __restrict__ suppB,
                                              const int2* __restrict__ csr,
                                              const int* __restrict__ offs,
                                              const int* __restrict__ counts,
                                              const float* __restrict__ bias,
                                              void* __restrict__ outp) {
  const int wid = (blockIdx.x * 256 + threadIdx.x) >> 6;
  const int lane = threadIdx.x & 63;
  if (wid >= NNODES) return;
  const int start = offs[wid], deg = counts[wid];
  const int2* e = csr + start;
  const uint32_t* sb = suppB + lane;
  float ax = 0.f, ay = 0.f;
  int i = 0;
  for (; i + 8 <= deg; i += 8) {
    int2 e0 = e[i], e1 = e[i + 1], e2 = e[i + 2], e3 = e[i + 3];
    int2 e4 = e[i + 4], e5 = e[i + 5], e6 = e[i + 6], e7 = e[i + 7];
    uint32_t h0 = sb[(size_t)e0.x * 64];
    uint32_t h1 = sb[(size_t)e1.x * 64];
    uint32_t h2 = sb[(size_t)e2.x * 64];
    uint32_t h3 = sb[(size_t)e3.x * 64];
    uint32_t h4 = sb[(size_t)e4.x * 64];
    uint32_t h5 = sb[(size_t)e5.x * 64];
    uint32_t h6 = sb[(size_t)e6.x * 64];
    uint32_t h7 = sb[(size_t)e7.x * 64];
    float v0 = __int_as_float(e0.y), v1 = __int_as_float(e1.y);
    float v2 = __int_as_float(e2.y), v3 = __int_as_float(e3.y);
    float v4 = __int_as_float(e4.y), v5 = __int_as_float(e5.y);
    float v6 = __int_as_float(e6.y), v7 = __int_as_float(e7.y);
    ax += v0 * bflo(h0); ay += v0 * bfhi(h0);
    ax += v1 * bflo(h1); ay += v1 * bfhi(h1);
    ax += v2 * bflo(h2); ay += v2 * bfhi(h2);
    ax += v3 * bflo(h3); ay += v3 * bfhi(h3);
    ax += v4 * bflo(h4); ay += v4 * bfhi(h4);
    ax += v5 * bflo(h5); ay += v5 * bfhi(h5);
    ax += v6 * bflo(h6); ay += v6 * bfhi(h6);
    ax += v7 * bflo(h7); ay += v7 * bfhi(h7);
  }
  for (; i < deg; ++i) {
    int2 e0 = e[i];
    uint32_t h = sb[(size_t)e0.x * 64];
    float v = __int_as_float(e0.y);
    ax += v * bflo(h);
    ay += v * bfhi(h);
  }
  float bx = bias[lane * 2], by = bias[lane * 2 + 1];
  float ox = fmaxf(ax + bx, 0.f), oy = fmaxf(ay + by, 0.f);
  if (OUTBF) {
    ((uint32_t*)outp)[(size_t)wid * 64 + lane] = (uint32_t)f2bf(ox) | ((uint32_t)f2bf(oy) << 16);
  } else {
    *reinterpret_cast<float2*>((float*)outp + (size_t)wid * 128 + lane * 2) = make_float2(ox, oy);
  }
}

// ============ launch ============
extern "C" void kernel_launch(void* const* d_in, const int* in_sizes, int n_in,
                              void* d_out, int out_size, void* d_ws, size_t ws_size,
                              hipStream_t stream) {
  const float* x = (const float*)d_in[0];
  const int* senders = (const int*)d_in[1];
  const int* recv = (const int*)d_in[2];
  const float* ev = (const float*)d_in[3];
  const float* W1 = (const float*)d_in[4];
  const float* b1 = (const float*)d_in[5];
  const float* W2 = (const float*)d_in[6];
  const float* b2 = (const float*)d_in[7];
  float* out = (float*)d_out;

  char* ws = (char*)d_ws;
  uint16_t* suppB = (uint16_t*)ws;            // 25,600,000 B  bf16 support table
  int2* csr = (int2*)(ws + 25600000);         // 25,600,000 B  final CSR (s, ev)
  char* bufB = ws + 51200000;                 // 25,600,000 B  pass1 buf, later h1 bf16
  int* offs = (int*)(ws + 76800000);          // 400,000 B
  int* counts = (int*)(ws + 77200000);        // 400,000 B
  int* bcount = (int*)(ws + 77600000);        // 12,500 B
  int* bcursor = (int*)(ws + 77612800);       // 12,500 B
  int* boffs = (int*)(ws + 77625600);         // 12,504 B
  uint16_t* wT = (uint16_t*)(ws + 77638400);  // 65,536 B  (end ~77.7 MB)

  hipMemsetAsync(bcount, 0, NBUCK * sizeof(int), stream);
  k_bhist<<<HBLK, 256, 0, stream>>>(recv, bcount);
  k_bscan<<<1, 1024, 0, stream>>>(bcount, boffs, bcursor);
  k_pass1<<<2048, 256, 0, stream>>>(senders, recv, ev, bcursor, (uint2*)bufB);
  k_pass2<<<NBUCK, 256, 0, stream>>>((const uint2*)bufB, boffs, offs, counts, csr);
  k_wprep<<<2, 256, 0, stream>>>(W1, W2, wT);

  // layer 1
  k_gemm<true><<<(NNODES + 63) / 64, 256, 0, stream>>>(x, wT, suppB);
  k_spmm<true><<<(NNODES * 64) / 256, 256, 0, stream>>>((const uint32_t*)suppB, csr, offs,
                                                        counts, b1, bufB);
  // layer 2
  k_gemm<false><<<(NNODES + 63) / 64, 256, 0, stream>>>(bufB, wT + 16384, suppB);
  k_spmm<false><<<(NNODES * 64) / 256, 256, 0, stream>>>((const uint32_t*)suppB, csr, offs,
                                                         counts, b2, out);
}

// Round 4
// 506.532 us; speedup vs baseline: 1.9351x; 1.4365x over previous
//
#include <hip/hip_runtime.h>
#include <cstdint>
#include <cstddef>

#define NNODES 100000
#define NEDGES 3200000
#define NF 128

// coarse buckets: 256 nodes each
#define S1_SHIFT 8
#define S1_BW 256
#define S1_NB ((NNODES + S1_BW - 1) / S1_BW)  // 391
#define S1_CH 8192
#define S1_T 512
#define S1_GRID ((NEDGES + S1_CH - 1) / S1_CH)  // 391

typedef __attribute__((ext_vector_type(8))) short short8v;
typedef __attribute__((ext_vector_type(4))) float float4v;

static __device__ __forceinline__ uint16_t f2bf(float f) {
  uint32_t u = __float_as_uint(f);
  return (uint16_t)((u + 0x7fffu + ((u >> 16) & 1u)) >> 16);  // RNE
}
static __device__ __forceinline__ float bflo(uint32_t u) { return __uint_as_float(u << 16); }
static __device__ __forceinline__ float bfhi(uint32_t u) { return __uint_as_float(u & 0xffff0000u); }

// ============ bucket histogram (LDS-privatized) ============
#define HBLK 256
__global__ __launch_bounds__(256) void k_bhist(const int* __restrict__ recv,
                                               int* __restrict__ bcount) {
  __shared__ int h[S1_NB];
  for (int i = threadIdx.x; i < S1_NB; i += 256) h[i] = 0;
  __syncthreads();
  const int stride = HBLK * 256;
  for (int i = blockIdx.x * 256 + threadIdx.x; i < NEDGES; i += stride)
    atomicAdd(&h[recv[i] >> S1_SHIFT], 1);
  __syncthreads();
  for (int i = threadIdx.x; i < S1_NB; i += 256) {
    int v = h[i];
    if (v) atomicAdd(&bcount[i], v);
  }
}

// ============ bucket exclusive scan (single block, 391 <= 512) ============
__global__ __launch_bounds__(512) void k_bscan(const int* __restrict__ bcount,
                                               int* __restrict__ boffs,
                                               int* __restrict__ bcursor) {
  __shared__ int sd[512];
  int t = threadIdx.x;
  int v = (t < S1_NB) ? bcount[t] : 0;
  sd[t] = v;
  __syncthreads();
  for (int off = 1; off < 512; off <<= 1) {
    int x = (t >= off) ? sd[t - off] : 0;
    __syncthreads();
    sd[t] += x;
    __syncthreads();
  }
  if (t < S1_NB) {
    int o = sd[t] - v;
    boffs[t] = o;
    bcursor[t] = o;
  }
  if (t == S1_NB - 1) boffs[S1_NB] = sd[t];
}

// ============ pass 1: block-local counting sort by coarse bucket, run flush ============
__global__ __launch_bounds__(S1_T, 4) void k_sort1(const int* __restrict__ send,
                                                   const int* __restrict__ recv,
                                                   const float* __restrict__ ev,
                                                   int* __restrict__ bcursor,
                                                   uint2* __restrict__ buf) {
  __shared__ uint2 sbuf[S1_CH];     // 64 KB
  __shared__ int h[S1_NB];          // hist, then insert-cursor
  __shared__ int hoff[S1_NB];       // exclusive offsets
  __shared__ int gb[S1_NB];         // global base per bucket
  __shared__ int sd[S1_T];
  const int t = threadIdx.x;
  const int base = blockIdx.x * S1_CH;
  const int nb = min(S1_CH, NEDGES - base);
  for (int i = t; i < S1_NB; i += S1_T) h[i] = 0;
  __syncthreads();
  for (int i = t; i < nb; i += S1_T) atomicAdd(&h[recv[base + i] >> S1_SHIFT], 1);
  __syncthreads();
  int v = (t < S1_NB) ? h[t] : 0;
  sd[t] = v;
  __syncthreads();
  for (int off = 1; off < S1_T; off <<= 1) {
    int x = (t >= off) ? sd[t - off] : 0;
    __syncthreads();
    sd[t] += x;
    __syncthreads();
  }
  if (t < S1_NB) {
    hoff[t] = sd[t] - v;
    if (v) gb[t] = atomicAdd(&bcursor[t], v);
    h[t] = 0;  // reuse as cursor
  }
  __syncthreads();
  for (int i = t; i < nb; i += S1_T) {
    int s = send[base + i];
    int r = recv[base + i];
    float w = ev[base + i];
    int b = r >> S1_SHIFT;
    int slot = hoff[b] + atomicAdd(&h[b], 1);
    sbuf[slot] = make_uint2((uint32_t)s | ((uint32_t)(r & (S1_BW - 1)) << 17),
                            __float_as_uint(w));
  }
  __syncthreads();
  for (int i = t; i < nb; i += S1_T) {
    // largest b with hoff[b] <= i (ties resolve to the non-empty bucket)
    int lo = 0, hi = S1_NB - 1;
    while (lo < hi) {
      int mid = (lo + hi + 1) >> 1;
      if (hoff[mid] <= i) lo = mid; else hi = mid - 1;
    }
    buf[gb[lo] + (i - hoff[lo])] = sbuf[i];
  }
}

// ============ pass 2: per-bucket sort to node granularity -> final CSR ============
__global__ __launch_bounds__(256) void k_pass2(const uint2* __restrict__ buf,
                                               const int* __restrict__ boffs,
                                               int* __restrict__ offs,
                                               int* __restrict__ counts,
                                               int2* __restrict__ csr) {
  __shared__ int hcnt[S1_BW], hoff2[S1_BW], sd[S1_BW];
  const int b = blockIdx.x, t = threadIdx.x;
  const int bstart = boffs[b], bend = boffs[b + 1];
  const int nb = bend - bstart;
  hcnt[t] = 0;
  __syncthreads();
  for (int i = t; i < nb; i += 256) atomicAdd(&hcnt[buf[bstart + i].x >> 17], 1);
  __syncthreads();
  int v = hcnt[t];
  sd[t] = v;
  __syncthreads();
  for (int off = 1; off < 256; off <<= 1) {
    int x = (t >= off) ? sd[t - off] : 0;
    __syncthreads();
    sd[t] += x;
    __syncthreads();
  }
  int excl = sd[t] - v;
  hoff2[t] = excl;
  int node = b * S1_BW + t;
  if (node < NNODES) {
    offs[node] = bstart + excl;
    counts[node] = v;
  }
  hcnt[t] = 0;
  __syncthreads();
  for (int i = t; i < nb; i += 256) {
    uint2 e = buf[bstart + i];
    uint32_t rl = e.x >> 17;
    int pos = bstart + hoff2[rl] + atomicAdd(&hcnt[rl], 1);
    csr[pos] = make_int2((int)(e.x & 0x1FFFFu), (int)e.y);
  }
}

// ============ W -> bf16, transposed [n][k] ============
__global__ __launch_bounds__(256) void k_wprep(const float* __restrict__ W1,
                                               const float* __restrict__ W2,
                                               uint16_t* __restrict__ wT) {
  const float* W = blockIdx.x ? W2 : W1;
  uint16_t* o = wT + blockIdx.x * 16384;
  for (int i = threadIdx.x; i < 16384; i += 256) {
    int k = i >> 7, n = i & 127;
    o[n * 128 + k] = f2bf(W[i]);
  }
}

// ============ MFMA bf16 GEMM: Y[N,128](bf16) = X[N,128] @ W ============
template <bool XF32>
__global__ __launch_bounds__(256) void k_gemm(const void* __restrict__ Xv,
                                              const uint16_t* __restrict__ wT,
                                              uint16_t* __restrict__ Y) {
  __shared__ uint16_t sX[64 * 128];
  __shared__ uint16_t sWT[128 * 128];  // [n][k], swizzled 16B chunks
  const int t = threadIdx.x;
  const int r0 = blockIdx.x * 64;
  {
    const uint4* src = (const uint4*)wT;
    uint4* dst = (uint4*)sWT;
#pragma unroll
    for (int j = 0; j < 8; ++j) {
      int i = j * 256 + t;
      int row = i >> 4;
      dst[(i & ~15) | ((i & 15) ^ (row & 7))] = src[i];
    }
  }
  if (XF32) {
    const float* X = (const float*)Xv;
    int r = t >> 2, c0 = (t & 3) * 32;
    int grow = r0 + r;
    if (grow >= NNODES) grow = NNODES - 1;
    const float* xp = X + (size_t)grow * 128 + c0;
    uint4* xdst = (uint4*)sX;
#pragma unroll
    for (int j = 0; j < 4; ++j) {
      float4 f0 = *(const float4*)(xp + j * 8);
      float4 f1 = *(const float4*)(xp + j * 8 + 4);
      uint4 vv;
      vv.x = (uint32_t)f2bf(f0.x) | ((uint32_t)f2bf(f0.y) << 16);
      vv.y = (uint32_t)f2bf(f0.z) | ((uint32_t)f2bf(f0.w) << 16);
      vv.z = (uint32_t)f2bf(f1.x) | ((uint32_t)f2bf(f1.y) << 16);
      vv.w = (uint32_t)f2bf(f1.z) | ((uint32_t)f2bf(f1.w) << 16);
      int kc = (c0 >> 3) + j;
      xdst[r * 16 + (kc ^ (r & 7))] = vv;
    }
  } else {
    const uint4* src = (const uint4*)((const char*)Xv + (size_t)r0 * 256);
    uint4* xdst = (uint4*)sX;
    size_t maxByte = (size_t)NNODES * 256 - (size_t)r0 * 256;
#pragma unroll
    for (int j = 0; j < 4; ++j) {
      int i = j * 256 + t;
      int row = i >> 4;
      uint4 vv = ((size_t)i * 16 < maxByte) ? src[i] : make_uint4(0, 0, 0, 0);
      xdst[(i & ~15) | ((i & 15) ^ (row & 7))] = vv;
    }
  }
  __syncthreads();
  const int l = t & 63, w = t >> 6;
  const int m16 = l & 15, kb = l >> 4;
  const int arow = w * 16 + m16;
  short8v a[4];
#pragma unroll
  for (int ks = 0; ks < 4; ++ks) {
    int elem = (ks * 32 + kb * 8) ^ ((arow & 7) << 3);
    a[ks] = *reinterpret_cast<const short8v*>(&sX[arow * 128 + elem]);
  }
  float4v acc[8] = {};
#pragma unroll
  for (int nt = 0; nt < 8; ++nt) {
    int brow = nt * 16 + m16;
    int bswz = (brow & 7) << 3;
    int bbase = brow * 128;
#pragma unroll
    for (int ks = 0; ks < 4; ++ks) {
      short8v bb = *reinterpret_cast<const short8v*>(&sWT[bbase + ((ks * 32 + kb * 8) ^ bswz)]);
      acc[nt] = __builtin_amdgcn_mfma_f32_16x16x32_bf16(a[ks], bb, acc[nt], 0, 0, 0);
    }
  }
  const int orow0 = r0 + w * 16 + kb * 4;
#pragma unroll
  for (int nt = 0; nt < 8; ++nt) {
    int col = nt * 16 + m16;
#pragma unroll
    for (int q = 0; q < 4; ++q) {
      int grow = orow0 + q;
      if (grow < NNODES) Y[(size_t)grow * 128 + col] = f2bf(acc[nt][q]);
    }
  }
}

// ============ SpMM + bias + relu (bf16 gather, 4B/lane) ============
template <bool OUTBF>
__global__ __launch_bounds__(256) void k_spmm(const uint32_t* __restrict__ suppB,
                                              const int2* __restrict__ csr,
                                              const int* __restrict__ offs,
                                              const int* __restrict__ counts,
                                              const float* __restrict__ bias,
                                              void* __restrict__ outp) {
  const int wid = (blockIdx.x * 256 + threadIdx.x) >> 6;
  const int lane = threadIdx.x & 63;
  if (wid >= NNODES) return;
  const int start = offs[wid], deg = counts[wid];
  const int2* e = csr + start;
  const uint32_t* sb = suppB + lane;
  float ax = 0.f, ay = 0.f;
  int i = 0;
  for (; i + 8 <= deg; i += 8) {
    int2 e0 = e[i], e1 = e[i + 1], e2 = e[i + 2], e3 = e[i + 3];
    int2 e4 = e[i + 4], e5 = e[i + 5], e6 = e[i + 6], e7 = e[i + 7];
    uint32_t h0 = sb[(size_t)e0.x * 64];
    uint32_t h1 = sb[(size_t)e1.x * 64];
    uint32_t h2 = sb[(size_t)e2.x * 64];
    uint32_t h3 = sb[(size_t)e3.x * 64];
    uint32_t h4 = sb[(size_t)e4.x * 64];
    uint32_t h5 = sb[(size_t)e5.x * 64];
    uint32_t h6 = sb[(size_t)e6.x * 64];
    uint32_t h7 = sb[(size_t)e7.x * 64];
    float v0 = __int_as_float(e0.y), v1 = __int_as_float(e1.y);
    float v2 = __int_as_float(e2.y), v3 = __int_as_float(e3.y);
    float v4 = __int_as_float(e4.y), v5 = __int_as_float(e5.y);
    float v6 = __int_as_float(e6.y), v7 = __int_as_float(e7.y);
    ax += v0 * bflo(h0); ay += v0 * bfhi(h0);
    ax += v1 * bflo(h1); ay += v1 * bfhi(h1);
    ax += v2 * bflo(h2); ay += v2 * bfhi(h2);
    ax += v3 * bflo(h3); ay += v3 * bfhi(h3);
    ax += v4 * bflo(h4); ay += v4 * bfhi(h4);
    ax += v5 * bflo(h5); ay += v5 * bfhi(h5);
    ax += v6 * bflo(h6); ay += v6 * bfhi(h6);
    ax += v7 * bflo(h7); ay += v7 * bfhi(h7);
  }
  for (; i < deg; ++i) {
    int2 e0 = e[i];
    uint32_t h = sb[(size_t)e0.x * 64];
    float v = __int_as_float(e0.y);
    ax += v * bflo(h);
    ay += v * bfhi(h);
  }
  float bx = bias[lane * 2], by = bias[lane * 2 + 1];
  float ox = fmaxf(ax + bx, 0.f), oy = fmaxf(ay + by, 0.f);
  if (OUTBF) {
    ((uint32_t*)outp)[(size_t)wid * 64 + lane] = (uint32_t)f2bf(ox) | ((uint32_t)f2bf(oy) << 16);
  } else {
    *reinterpret_cast<float2*>((float*)outp + (size_t)wid * 128 + lane * 2) = make_float2(ox, oy);
  }
}

// ============ launch ============
extern "C" void kernel_launch(void* const* d_in, const int* in_sizes, int n_in,
                              void* d_out, int out_size, void* d_ws, size_t ws_size,
                              hipStream_t stream) {
  const float* x = (const float*)d_in[0];
  const int* senders = (const int*)d_in[1];
  const int* recv = (const int*)d_in[2];
  const float* ev = (const float*)d_in[3];
  const float* W1 = (const float*)d_in[4];
  const float* b1 = (const float*)d_in[5];
  const float* W2 = (const float*)d_in[6];
  const float* b2 = (const float*)d_in[7];
  float* out = (float*)d_out;

  char* ws = (char*)d_ws;
  uint16_t* suppB = (uint16_t*)ws;            // 25,600,000 B  bf16 support table
  int2* csr = (int2*)(ws + 25600000);         // 25,600,000 B  final CSR (s, ev)
  char* bufB = ws + 51200000;                 // 25,600,000 B  pass1 buf, later h1 bf16
  int* offs = (int*)(ws + 76800000);          // 400,000 B
  int* counts = (int*)(ws + 77200000);        // 400,000 B
  int* bcount = (int*)(ws + 77600000);        // S1_NB ints
  int* bcursor = (int*)(ws + 77612800);       // S1_NB ints
  int* boffs = (int*)(ws + 77625600);         // S1_NB+1 ints
  uint16_t* wT = (uint16_t*)(ws + 77638400);  // 65,536 B  (end ~77.7 MB)

  hipMemsetAsync(bcount, 0, S1_NB * sizeof(int), stream);
  k_bhist<<<HBLK, 256, 0, stream>>>(recv, bcount);
  k_bscan<<<1, 512, 0, stream>>>(bcount, boffs, bcursor);
  k_sort1<<<S1_GRID, S1_T, 0, stream>>>(senders, recv, ev, bcursor, (uint2*)bufB);
  k_pass2<<<S1_NB, 256, 0, stream>>>((const uint2*)bufB, boffs, offs, counts, csr);
  k_wprep<<<2, 256, 0, stream>>>(W1, W2, wT);

  // layer 1
  k_gemm<true><<<(NNODES + 63) / 64, 256, 0, stream>>>(x, wT, suppB);
  k_spmm<true><<<(NNODES * 64) / 256, 256, 0, stream>>>((const uint32_t*)suppB, csr, offs,
                                                        counts, b1, bufB);
  // layer 2
  k_gemm<false><<<(NNODES + 63) / 64, 256, 0, stream>>>(bufB, wT + 16384, suppB);
  k_spmm<false><<<(NNODES * 64) / 256, 256, 0, stream>>>((const uint32_t*)suppB, csr, offs,
                                                         counts, b2, out);
}